// Round 8
// baseline (29.135 us; speedup 1.0000x reference)
//
#include <hip/hip_runtime.h>
#include <math.h>

#define TLEN 4096
#define LEVELS 4
#define CHANS 32
#define SLOPE 10.0f

__device__ __forceinline__ float clamp30(float v) {
    return __builtin_amdgcn_fmed3f(v, -30.f, 30.f);
}

// d = hi * (sigmoid(S*(hi-b)) + sigmoid(-S*(hi+b)))
//   = hi * (2 + ea + eb) / ((1+ea)*(1+eb)),  ea=exp(-S*(hi-b)), eb=exp(S*(hi+b))
// clamp exp args to +-30 (fmed3) so ea*eb stays finite -> no inf*0 NaN.
__device__ __forceinline__ float sgate(float hi, float b) {
    const float ea = __expf(clamp30(-SLOPE * (hi - b)));
    const float eb = __expf(clamp30( SLOPE * (hi + b)));
    return hi * (2.f + ea + eb) * __builtin_amdgcn_rcpf((1.f + ea) * (1.f + eb));
}

// Fully-register 4-level cascade: no LDS, no barriers.
// Thread t owns outputs {d1[8t..8t+7], d2[4t..4t+3], d3[2t..2t+1], d4[t], yl[t]}
// which depend only on x[16t .. 16t+45] (circular). Redundant halo lo-chain
// is recomputed per thread; extra reads hit L1/L2 (neighbors own them).
__global__ __launch_bounds__(256) void lwpt_kernel(
    const float* __restrict__ x, const float* __restrict__ h_lo,
    const float* __restrict__ bias, float* __restrict__ out)
{
    const int bc  = blockIdx.x;          // row index (b*32 + c)
    const int c   = bc & (CHANS - 1);
    const int tid = threadIdx.x;

    const float* xrow = x   + (size_t)bc * TLEN;
    float*       orow = out + (size_t)bc * TLEN;

    // filters: h_lo is [C, LEVEL, 4] f32 -> one float4 per (c,l)
    const float4 k0v = ((const float4*)h_lo)[c * LEVELS + 0];
    const float4 k1v = ((const float4*)h_lo)[c * LEVELS + 1];
    const float4 k2v = ((const float4*)h_lo)[c * LEVELS + 2];
    const float4 k3v = ((const float4*)h_lo)[c * LEVELS + 3];
    const float b0 = bias[c * LEVELS + 0];
    const float b1 = bias[c * LEVELS + 1];
    const float b2 = bias[c * LEVELS + 2];
    const float b3 = bias[c * LEVELS + 3];

    // ---- load x[16t .. 16t+45] (mod 4096): 11 x float4 + 1 x float2, all aligned
    float in[46];
    const int base = 16 * tid;
    #pragma unroll
    for (int k = 0; k < 4; ++k) {                 // owned 16, in-bounds
        const float4 v = *(const float4*)(xrow + base + 4 * k);
        in[4*k+0] = v.x; in[4*k+1] = v.y; in[4*k+2] = v.z; in[4*k+3] = v.w;
    }
    #pragma unroll
    for (int k = 0; k < 7; ++k) {                 // halo 28, wraps for tid=255
        const float4 v = *(const float4*)(xrow + ((base + 16 + 4 * k) & (TLEN - 1)));
        in[16+4*k+0] = v.x; in[16+4*k+1] = v.y; in[16+4*k+2] = v.z; in[16+4*k+3] = v.w;
    }
    {
        const float2 e = *(const float2*)(xrow + ((base + 44) & (TLEN - 1)));
        in[44] = e.x; in[45] = e.y;
    }

    // ---- Level 1: lo1[22] (8 owned + 14 halo), d1 for owned 8
    float lo1[22];
    #pragma unroll
    for (int j = 0; j < 22; ++j)
        lo1[j] = in[2*j]*k0v.x + in[2*j+1]*k0v.y + in[2*j+2]*k0v.z + in[2*j+3]*k0v.w;
    {
        float dd[8];
        #pragma unroll
        for (int j = 0; j < 8; ++j) {
            const float hi = in[2*j]*k0v.w - in[2*j+1]*k0v.z + in[2*j+2]*k0v.y - in[2*j+3]*k0v.x;
            dd[j] = sgate(hi, b0);
        }
        float4* o4 = (float4*)(orow + 2048);
        o4[2*tid]   = make_float4(dd[0], dd[1], dd[2], dd[3]);
        o4[2*tid+1] = make_float4(dd[4], dd[5], dd[6], dd[7]);
    }

    // ---- Level 2: lo2[10] (4 owned + 6 halo), d2 for owned 4
    float lo2[10];
    #pragma unroll
    for (int j = 0; j < 10; ++j)
        lo2[j] = lo1[2*j]*k1v.x + lo1[2*j+1]*k1v.y + lo1[2*j+2]*k1v.z + lo1[2*j+3]*k1v.w;
    {
        float dd[4];
        #pragma unroll
        for (int j = 0; j < 4; ++j) {
            const float hi = lo1[2*j]*k1v.w - lo1[2*j+1]*k1v.z + lo1[2*j+2]*k1v.y - lo1[2*j+3]*k1v.x;
            dd[j] = sgate(hi, b1);
        }
        ((float4*)(orow + 1024))[tid] = make_float4(dd[0], dd[1], dd[2], dd[3]);
    }

    // ---- Level 3: lo3[4] (2 owned + 2 halo), d3 for owned 2
    float lo3[4];
    #pragma unroll
    for (int j = 0; j < 4; ++j)
        lo3[j] = lo2[2*j]*k2v.x + lo2[2*j+1]*k2v.y + lo2[2*j+2]*k2v.z + lo2[2*j+3]*k2v.w;
    {
        float dd[2];
        #pragma unroll
        for (int j = 0; j < 2; ++j) {
            const float hi = lo2[2*j]*k2v.w - lo2[2*j+1]*k2v.z + lo2[2*j+2]*k2v.y - lo2[2*j+3]*k2v.x;
            dd[j] = sgate(hi, b2);
        }
        ((float2*)(orow + 512))[tid] = make_float2(dd[0], dd[1]);
    }

    // ---- Level 4: yl[t], d4[t]
    {
        const float lo = lo3[0]*k3v.x + lo3[1]*k3v.y + lo3[2]*k3v.z + lo3[3]*k3v.w;
        const float hi = lo3[0]*k3v.w - lo3[1]*k3v.z + lo3[2]*k3v.y - lo3[3]*k3v.x;
        orow[tid]       = lo;
        orow[256 + tid] = sgate(hi, b3);
    }
}

extern "C" void kernel_launch(void* const* d_in, const int* in_sizes, int n_in,
                              void* d_out, int out_size, void* d_ws, size_t ws_size,
                              hipStream_t stream) {
    const float* x    = (const float*)d_in[0];
    const float* h_lo = (const float*)d_in[1];
    const float* bias = (const float*)d_in[2];
    float* out = (float*)d_out;

    dim3 grid(128 * CHANS);
    dim3 block(256);
    lwpt_kernel<<<grid, block, 0, stream>>>(x, h_lo, bias, out);
}

// Round 9
// 28.598 us; speedup vs baseline: 1.0188x; 1.0188x over previous
//
#include <hip/hip_runtime.h>
#include <math.h>

#define TLEN 4096
#define LEVELS 4
#define CHANS 32
#define SLOPE 10.0f

__device__ __forceinline__ float clamp30(float v) {
    return __builtin_amdgcn_fmed3f(v, -30.f, 30.f);
}

// d = hi * (sigmoid(S*(hi-b)) + sigmoid(-S*(hi+b)))
//   = hi * (2 + ea + eb) / ((1+ea)*(1+eb)),  ea=exp(-S*(hi-b)), eb=exp(S*(hi+b))
// clamp exp args to +-30 (fmed3) so ea*eb stays finite -> no inf*0 NaN.
__device__ __forceinline__ float sgate(float hi, float b) {
    const float ea = __expf(clamp30(-SLOPE * (hi - b)));
    const float eb = __expf(clamp30( SLOPE * (hi + b)));
    return hi * (2.f + ea + eb) * __builtin_amdgcn_rcpf((1.f + ea) * (1.f + eb));
}

// Two fused super-phases, ONE barrier:
//  Phase A (global->regs): thread t loads x[16t..16t+21] (22 floats, 6 vec loads),
//    computes lo1[10] (8 owned + 2 halo), d1[8], lo2[4], d2[4];
//    writes lo2 (float4) to LDS, d1/d2 to global.
//  Phase B (LDS->regs): reads lo2[4t..4t+9] (10 floats), computes lo3[4]
//    (2 owned + 2 redundant), d3[2], yl[1], d4[1]; writes to global.
__global__ __launch_bounds__(256) void lwpt_kernel(
    const float* __restrict__ x, const float* __restrict__ h_lo,
    const float* __restrict__ bias, float* __restrict__ out)
{
    __shared__ float bufB[1024];   // full lo2 row

    const int bc  = blockIdx.x;          // row index (b*32 + c)
    const int c   = bc & (CHANS - 1);
    const int tid = threadIdx.x;

    const float* xrow = x   + (size_t)bc * TLEN;
    float*       orow = out + (size_t)bc * TLEN;

    // filters: h_lo is [C, LEVEL, 4] f32 -> one float4 per (c,l)
    const float4 k0v = ((const float4*)h_lo)[c * LEVELS + 0];
    const float4 k1v = ((const float4*)h_lo)[c * LEVELS + 1];
    const float4 k2v = ((const float4*)h_lo)[c * LEVELS + 2];
    const float4 k3v = ((const float4*)h_lo)[c * LEVELS + 3];
    const float b0 = bias[c * LEVELS + 0];
    const float b1 = bias[c * LEVELS + 1];
    const float b2 = bias[c * LEVELS + 2];
    const float b3 = bias[c * LEVELS + 3];

    // ---- Phase A: load x[16t .. 16t+21] (mod 4096): 5 x float4 + 1 x float2
    float in[22];
    const int base = 16 * tid;
    #pragma unroll
    for (int k = 0; k < 4; ++k) {                 // owned 16, in-bounds
        const float4 v = *(const float4*)(xrow + base + 4 * k);
        in[4*k+0] = v.x; in[4*k+1] = v.y; in[4*k+2] = v.z; in[4*k+3] = v.w;
    }
    {
        const float4 v = *(const float4*)(xrow + ((base + 16) & (TLEN - 1)));
        in[16] = v.x; in[17] = v.y; in[18] = v.z; in[19] = v.w;
        const float2 e = *(const float2*)(xrow + ((base + 20) & (TLEN - 1)));
        in[20] = e.x; in[21] = e.y;
    }

    // lo1[10]: 8 owned + 2 halo
    float lo1[10];
    #pragma unroll
    for (int j = 0; j < 10; ++j)
        lo1[j] = in[2*j]*k0v.x + in[2*j+1]*k0v.y + in[2*j+2]*k0v.z + in[2*j+3]*k0v.w;

    // d1[8] -> orow[2048..4096)
    {
        float dd[8];
        #pragma unroll
        for (int j = 0; j < 8; ++j) {
            const float hi = in[2*j]*k0v.w - in[2*j+1]*k0v.z + in[2*j+2]*k0v.y - in[2*j+3]*k0v.x;
            dd[j] = sgate(hi, b0);
        }
        float4* o4 = (float4*)(orow + 2048);
        o4[2*tid]   = make_float4(dd[0], dd[1], dd[2], dd[3]);
        o4[2*tid+1] = make_float4(dd[4], dd[5], dd[6], dd[7]);
    }

    // lo2[4] -> LDS, d2[4] -> orow[1024..2048)
    {
        float lo[4], dd[4];
        #pragma unroll
        for (int j = 0; j < 4; ++j) {
            const float a0 = lo1[2*j], a1 = lo1[2*j+1], a2 = lo1[2*j+2], a3 = lo1[2*j+3];
            lo[j] = a0*k1v.x + a1*k1v.y + a2*k1v.z + a3*k1v.w;
            const float hi = a0*k1v.w - a1*k1v.z + a2*k1v.y - a3*k1v.x;
            dd[j] = sgate(hi, b1);
        }
        ((float4*)bufB)[tid] = make_float4(lo[0], lo[1], lo[2], lo[3]);
        ((float4*)(orow + 1024))[tid] = make_float4(dd[0], dd[1], dd[2], dd[3]);
    }
    __syncthreads();

    // ---- Phase B: lo2[4t..4t+9] from LDS; levels 3+4 in registers
    {
        float t10[10];
        const float4 v0 = ((const float4*)bufB)[tid];
        const float4 v1 = *(const float4*)(bufB + ((4 * tid + 4) & 1023));
        const float2 e  = *(const float2*)(bufB + ((4 * tid + 8) & 1023));
        t10[0] = v0.x; t10[1] = v0.y; t10[2] = v0.z; t10[3] = v0.w;
        t10[4] = v1.x; t10[5] = v1.y; t10[6] = v1.z; t10[7] = v1.w;
        t10[8] = e.x;  t10[9] = e.y;

        // lo3[4]: 2 owned + 2 redundant (next thread's), enables level 4 in-reg
        float lo3[4];
        #pragma unroll
        for (int j = 0; j < 4; ++j)
            lo3[j] = t10[2*j]*k2v.x + t10[2*j+1]*k2v.y + t10[2*j+2]*k2v.z + t10[2*j+3]*k2v.w;

        // d3[2] -> orow[512..1024)
        {
            float dd[2];
            #pragma unroll
            for (int j = 0; j < 2; ++j) {
                const float hi = t10[2*j]*k2v.w - t10[2*j+1]*k2v.z + t10[2*j+2]*k2v.y - t10[2*j+3]*k2v.x;
                dd[j] = sgate(hi, b2);
            }
            ((float2*)(orow + 512))[tid] = make_float2(dd[0], dd[1]);
        }

        // level 4: yl -> orow[0..256), d4 -> orow[256..512)
        const float lo = lo3[0]*k3v.x + lo3[1]*k3v.y + lo3[2]*k3v.z + lo3[3]*k3v.w;
        const float hi = lo3[0]*k3v.w - lo3[1]*k3v.z + lo3[2]*k3v.y - lo3[3]*k3v.x;
        orow[tid]       = lo;
        orow[256 + tid] = sgate(hi, b3);
    }
}

extern "C" void kernel_launch(void* const* d_in, const int* in_sizes, int n_in,
                              void* d_out, int out_size, void* d_ws, size_t ws_size,
                              hipStream_t stream) {
    const float* x    = (const float*)d_in[0];
    const float* h_lo = (const float*)d_in[1];
    const float* bias = (const float*)d_in[2];
    float* out = (float*)d_out;

    dim3 grid(128 * CHANS);
    dim3 block(256);
    lwpt_kernel<<<grid, block, 0, stream>>>(x, h_lo, bias, out);
}

// Round 10
// 26.941 us; speedup vs baseline: 1.0814x; 1.0615x over previous
//
#include <hip/hip_runtime.h>
#include <math.h>

#define TLEN 4096
#define LEVELS 4
#define CHANS 32
#define SLOPE 10.0f

__device__ __forceinline__ float clamp30(float v) {
    return __builtin_amdgcn_fmed3f(v, -30.f, 30.f);
}

// d = hi * (sigmoid(S*(hi-b)) + sigmoid(-S*(hi+b)))
//   = hi * (2 + ea + eb) / ((1+ea)*(1+eb)),  ea=exp(-S*(hi-b)), eb=exp(S*(hi+b))
__device__ __forceinline__ float sgate(float hi, float b) {
    const float ea = __expf(clamp30(-SLOPE * (hi - b)));
    const float eb = __expf(clamp30( SLOPE * (hi + b)));
    return hi * (2.f + ea + eb) * __builtin_amdgcn_rcpf((1.f + ea) * (1.f + eb));
}

// 128-thread block = HALF a row (2048 samples). 2-wave barriers, 16 blocks/CU.
// Lanes 120..126 compute the deep-halo lo-chain entries (circular-correct:
// block-local halo index == row index mod level length for both halves).
__global__ __launch_bounds__(128, 8) void lwpt_kernel(
    const float* __restrict__ x, const float* __restrict__ h_lo,
    const float* __restrict__ bias, float* __restrict__ out)
{
    __shared__ float smem[1560];
    float* L1 = smem;          // lo1: 1024 owned + 14 halo   [0..1037]
    float* L2 = smem + 1040;   // lo2: 512 owned + 6 halo     [0..517]
    float* L3 = smem;          // lo3: 256 owned + 2 halo (reuses L1 space)

    const int bid = blockIdx.x;
    const int bc  = bid >> 1;            // row index (b*32 + c)
    const int hh  = bid & 1;             // which half of the row
    const int S   = hh << 11;            // 0 or 2048
    const int c   = bc & (CHANS - 1);
    const int tid = threadIdx.x;         // 0..127

    const float* xrow = x   + (size_t)bc * TLEN;
    float*       orow = out + (size_t)bc * TLEN;

    const float4 k0v = ((const float4*)h_lo)[c * LEVELS + 0];
    const float4 k1v = ((const float4*)h_lo)[c * LEVELS + 1];
    const float4 k2v = ((const float4*)h_lo)[c * LEVELS + 2];
    const float4 k3v = ((const float4*)h_lo)[c * LEVELS + 3];
    const float b0 = bias[c * LEVELS + 0];
    const float b1 = bias[c * LEVELS + 1];
    const float b2 = bias[c * LEVELS + 2];
    const float b3 = bias[c * LEVELS + 3];

    // ---- P1: level 1 from global regs; lo1 -> L1, d1 -> orow[2048+1024h ..)
    {
        float in[18];
        const int base = S + 16 * tid;           // owned loads in-bounds
        #pragma unroll
        for (int k = 0; k < 4; ++k) {
            const float4 v = *(const float4*)(xrow + base + 4 * k);
            in[4*k+0] = v.x; in[4*k+1] = v.y; in[4*k+2] = v.z; in[4*k+3] = v.w;
        }
        const float2 e = *(const float2*)(xrow + ((base + 16) & (TLEN - 1)));
        in[16] = e.x; in[17] = e.y;

        float lo[8], dd[8];
        #pragma unroll
        for (int j = 0; j < 8; ++j) {
            const float a0 = in[2*j], a1 = in[2*j+1], a2 = in[2*j+2], a3 = in[2*j+3];
            lo[j] = a0*k0v.x + a1*k0v.y + a2*k0v.z + a3*k0v.w;
            const float hi = a0*k0v.w - a1*k0v.z + a2*k0v.y - a3*k0v.x;
            dd[j] = sgate(hi, b0);
        }
        ((float4*)L1)[2*tid]   = make_float4(lo[0], lo[1], lo[2], lo[3]);
        ((float4*)L1)[2*tid+1] = make_float4(lo[4], lo[5], lo[6], lo[7]);
        float4* o4 = (float4*)(orow + 2048 + (S >> 1));
        o4[2*tid]   = make_float4(dd[0], dd[1], dd[2], dd[3]);
        o4[2*tid+1] = make_float4(dd[4], dd[5], dd[6], dd[7]);

        // deep halo: lanes 120..126 each produce lo1[1024+2s], lo1[1024+2s+1]
        if (tid >= 120 && tid < 127) {
            const int s = tid - 120;
            const int hb = S + 2048 + 4 * s;
            const float4 v  = *(const float4*)(xrow + (hb & (TLEN - 1)));
            const float2 e2 = *(const float2*)(xrow + ((hb + 4) & (TLEN - 1)));
            L1[1024 + 2*s]     = v.x*k0v.x + v.y*k0v.y + v.z*k0v.z + v.w*k0v.w;
            L1[1024 + 2*s + 1] = v.z*k0v.x + v.w*k0v.y + e2.x*k0v.z + e2.y*k0v.w;
        }
    }
    __syncthreads();

    // ---- P2: level 2; lo2 -> L2, d2 -> orow[1024+512h ..)
    {
        const float4 v0 = *(const float4*)(L1 + 8*tid);
        const float4 v1 = *(const float4*)(L1 + 8*tid + 4);
        const float2 e  = *(const float2*)(L1 + 8*tid + 8);
        float a[10];
        a[0]=v0.x; a[1]=v0.y; a[2]=v0.z; a[3]=v0.w;
        a[4]=v1.x; a[5]=v1.y; a[6]=v1.z; a[7]=v1.w;
        a[8]=e.x;  a[9]=e.y;

        float lo[4], dd[4];
        #pragma unroll
        for (int j = 0; j < 4; ++j) {
            const float a0 = a[2*j], a1 = a[2*j+1], a2 = a[2*j+2], a3 = a[2*j+3];
            lo[j] = a0*k1v.x + a1*k1v.y + a2*k1v.z + a3*k1v.w;
            const float hi = a0*k1v.w - a1*k1v.z + a2*k1v.y - a3*k1v.x;
            dd[j] = sgate(hi, b1);
        }
        ((float4*)L2)[tid] = make_float4(lo[0], lo[1], lo[2], lo[3]);
        ((float4*)(orow + 1024 + (S >> 2)))[tid] = make_float4(dd[0], dd[1], dd[2], dd[3]);

        if (tid >= 120 && tid < 126) {      // lo2 halo [512..517]
            const int s = tid - 120;
            const float2 u0 = *(const float2*)(L1 + 1024 + 2*s);
            const float2 u1 = *(const float2*)(L1 + 1024 + 2*s + 2);
            L2[512 + s] = u0.x*k1v.x + u0.y*k1v.y + u1.x*k1v.z + u1.y*k1v.w;
        }
    }
    __syncthreads();

    // ---- P3: level 3; lo3 -> L3 (reuses L1 space), d3 -> orow[512+256h ..)
    {
        const float4 v0 = *(const float4*)(L2 + 4*tid);
        const float2 e  = *(const float2*)(L2 + 4*tid + 4);
        float a[6];
        a[0]=v0.x; a[1]=v0.y; a[2]=v0.z; a[3]=v0.w; a[4]=e.x; a[5]=e.y;

        float lo[2], dd[2];
        #pragma unroll
        for (int j = 0; j < 2; ++j) {
            const float a0 = a[2*j], a1 = a[2*j+1], a2 = a[2*j+2], a3 = a[2*j+3];
            lo[j] = a0*k2v.x + a1*k2v.y + a2*k2v.z + a3*k2v.w;
            const float hi = a0*k2v.w - a1*k2v.z + a2*k2v.y - a3*k2v.x;
            dd[j] = sgate(hi, b2);
        }
        ((float2*)L3)[tid] = make_float2(lo[0], lo[1]);
        ((float2*)(orow + 512 + (S >> 3)))[tid] = make_float2(dd[0], dd[1]);

        if (tid >= 120 && tid < 122) {      // lo3 halo [256,257]
            const int s = tid - 120;
            const float2 u0 = *(const float2*)(L2 + 512 + 2*s);
            const float2 u1 = *(const float2*)(L2 + 512 + 2*s + 2);
            L3[256 + s] = u0.x*k2v.x + u0.y*k2v.y + u1.x*k2v.z + u1.y*k2v.w;
        }
    }
    __syncthreads();

    // ---- P4: level 4; yl -> orow[128h + t], d4 -> orow[256 + 128h + t]
    {
        const float2 a01 = *(const float2*)(L3 + 2*tid);
        const float2 a23 = *(const float2*)(L3 + 2*tid + 2);
        const float a0 = a01.x, a1 = a01.y, a2 = a23.x, a3 = a23.y;
        const float lo = a0*k3v.x + a1*k3v.y + a2*k3v.z + a3*k3v.w;
        const float hi = a0*k3v.w - a1*k3v.z + a2*k3v.y - a3*k3v.x;
        orow[(S >> 4) + tid]       = lo;
        orow[256 + (S >> 4) + tid] = sgate(hi, b3);
    }
}

extern "C" void kernel_launch(void* const* d_in, const int* in_sizes, int n_in,
                              void* d_out, int out_size, void* d_ws, size_t ws_size,
                              hipStream_t stream) {
    const float* x    = (const float*)d_in[0];
    const float* h_lo = (const float*)d_in[1];
    const float* bias = (const float*)d_in[2];
    float* out = (float*)d_out;

    dim3 grid(128 * CHANS * 2);    // 2 blocks per row
    dim3 block(128);
    lwpt_kernel<<<grid, block, 0, stream>>>(x, h_lo, bias, out);
}